// Round 2
// baseline (2902.908 us; speedup 1.0000x reference)
//
#include <hip/hip_runtime.h>
#include <hip/hip_bf16.h>
#include <math.h>

// Problem constants
constexpr int kS = 512, kB = 64, kD = 1024, kH = 2048, kNH = 8;
constexpr int kM = kS * kB; // 32768 GEMM rows (sb index)

typedef __attribute__((ext_vector_type(8))) short bf16x8;
typedef __attribute__((ext_vector_type(4))) float f32x4;

#define GLB(p) ((const __attribute__((address_space(1))) unsigned int*)(p))
#define LDSP(p) ((__attribute__((address_space(3))) unsigned int*)(p))

__device__ __forceinline__ unsigned short f2bf(float f) {
  unsigned int u = __builtin_bit_cast(unsigned int, f);
  unsigned int r = (u + 0x7fffu + ((u >> 16) & 1u)) >> 16;
  return (unsigned short)r;
}

// ---- fp32 -> bf16 conversion (memory-bound, 8 elems/thread) ----
__global__ __launch_bounds__(256) void cvt_bf16(const float* __restrict__ src,
                                                unsigned short* __restrict__ dst,
                                                int n8) {
  int i = blockIdx.x * 256 + threadIdx.x;
  if (i >= n8) return;
  const float4* s4 = (const float4*)src;
  float4 v0 = s4[2 * i], v1 = s4[2 * i + 1];
  union { unsigned short u[8]; float4 f2[2]; } o; // 16B store
  o.u[0] = f2bf(v0.x); o.u[1] = f2bf(v0.y); o.u[2] = f2bf(v0.z); o.u[3] = f2bf(v0.w);
  o.u[4] = f2bf(v1.x); o.u[5] = f2bf(v1.y); o.u[6] = f2bf(v1.z); o.u[7] = f2bf(v1.w);
  *(float4*)(dst + (size_t)i * 8) = o.f2[0];
}

// ---- GEMM1 (bf16 MFMA) fused with relu + W_att epilogue ----
// LDS tiles are XOR-swizzled: physical 16B-slot segP = segL ^ ((row>>1)&3).
// Applied on the GLOBAL source (lane permutation within each row's 64B chunk,
// keeps coalescing + linear global_load_lds dest) and on the ds_read address.
// Pre-swizzle start banks were only 8 distinct (8-way conflict, 2.35e8 cycles);
// post-swizzle: exactly 2 accesses/bank -> free.
__global__ __launch_bounds__(256, 4) void gemm_fused(
    const unsigned short* __restrict__ Abf,   // [kM][kD] bf16
    const unsigned short* __restrict__ Wbf,   // [kH][kD] bf16
    const float* __restrict__ b_red,          // [kH]
    const float* __restrict__ W_att,          // [kNH][kH]
    float* __restrict__ logits)               // [kM][kNH] (pre-zeroed)
{
  __shared__ union {
    struct { unsigned short Ab[128 * 32]; unsigned short Bb[128 * 32]; } st; // 16 KB staging
    float et[32 * 132];                                                      // 16.9 KB epilogue tile
  } u;
  __shared__ float Wa[8 * 128]; // W_att slice for this n-tile

  const int tid = threadIdx.x;
  const int lane = tid & 63;
  const int w = tid >> 6;        // wave 0..3
  const int wr = w >> 1, wc = w & 1;

  // XCD-aware swizzle: 4096 blocks, 8 XCDs, 512 contiguous tiles per XCD
  int bid = blockIdx.x;
  int swz = (bid & 7) * 512 + (bid >> 3);
  const int nt = swz & 15, mt = swz >> 4;
  const int m0 = mt * 128, n0 = nt * 128;

  f32x4 acc[4][4] = {};

  for (int kt = 0; kt < kD / 32; ++kt) {
    const int k0 = kt * 32;
#pragma unroll
    for (int i = 0; i < 2; ++i) {
      const int ck = w * 2 + i;              // 16-row chunk id, 0..7
      const int row = ck * 16 + (lane >> 2); // 0..127
      const int segL = (lane & 3) ^ ((row >> 1) & 3); // pre-swizzled source slot
      const unsigned short* ga =
          Abf + (size_t)(m0 + row) * kD + k0 + segL * 8;
      __builtin_amdgcn_global_load_lds(GLB(ga), LDSP(&u.st.Ab[ck * 512 + lane * 8]), 16, 0, 0);
      const unsigned short* gb =
          Wbf + (size_t)(n0 + row) * kD + k0 + segL * 8;
      __builtin_amdgcn_global_load_lds(GLB(gb), LDSP(&u.st.Bb[ck * 512 + lane * 8]), 16, 0, 0);
    }
    __syncthreads();

    bf16x8 aF[4], bF[4];
    const int seg = lane >> 4;
#pragma unroll
    for (int m = 0; m < 4; ++m) {
      const int row = wr * 64 + m * 16 + (lane & 15);
      aF[m] = *(const bf16x8*)&u.st.Ab[row * 32 + (seg ^ ((row >> 1) & 3)) * 8];
    }
#pragma unroll
    for (int n = 0; n < 4; ++n) {
      const int row = wc * 64 + n * 16 + (lane & 15);
      bF[n] = *(const bf16x8*)&u.st.Bb[row * 32 + (seg ^ ((row >> 1) & 3)) * 8];
    }
#pragma unroll
    for (int m = 0; m < 4; ++m)
#pragma unroll
      for (int n = 0; n < 4; ++n)
        acc[m][n] = __builtin_amdgcn_mfma_f32_16x16x32_bf16(aF[m], bF[n], acc[m][n], 0, 0, 0);
    __syncthreads();
  }

  // ---- fused epilogue: logits[m0+r, a] += sum_h(relu(C+b_red)*W_att) ----
  // 4 chunks of 32 rows (keeps LDS at 21 KB -> 4 blocks/CU).
  float bias[4];
#pragma unroll
  for (int n = 0; n < 4; ++n) bias[n] = b_red[n0 + wc * 64 + n * 16 + (lane & 15)];

#pragma unroll 1
  for (int c = 0; c < 4; ++c) {
    if (wr == (c >> 1)) {
      // these 2 waves own rows c*32 .. c*32+31 of the C tile
#pragma unroll
      for (int m2 = 0; m2 < 2; ++m2) {
        const int m = (c & 1) * 2 + m2;
#pragma unroll
        for (int n = 0; n < 4; ++n) {
          const int colL = wc * 64 + n * 16 + (lane & 15);
#pragma unroll
          for (int j = 0; j < 4; ++j) {
            const int rowL = m2 * 16 + (lane >> 4) * 4 + j; // 0..31
            float v = acc[m][n][j] + bias[n];
            u.et[rowL * 132 + colL] = v > 0.f ? v : 0.f;
          }
        }
      }
    }
    if (c == 0 && wr == 1) {
      // waves 2,3 load the W_att slice meanwhile (only once)
      const int t = tid - 128; // 0..127
#pragma unroll
      for (int a = 0; a < 8; ++a) Wa[a * 128 + t] = W_att[a * kH + n0 + t];
    }
    __syncthreads();

    {
      const int row = tid >> 3;  // 0..31
      const int q = tid & 7;     // column eighth (strided)
      float pa[8] = {0.f, 0.f, 0.f, 0.f, 0.f, 0.f, 0.f, 0.f};
#pragma unroll
      for (int i = 0; i < 16; ++i) {
        const int col = q + i * 8;
        const float v = u.et[row * 132 + col];
#pragma unroll
        for (int a = 0; a < 8; ++a) pa[a] += v * Wa[a * 128 + col];
      }
#pragma unroll
      for (int a = 0; a < 8; ++a) {
        pa[a] += __shfl_xor(pa[a], 1);
        pa[a] += __shfl_xor(pa[a], 2);
        pa[a] += __shfl_xor(pa[a], 4);
      }
      if (q == 0) {
        const int gr = m0 + c * 32 + row;
#pragma unroll
        for (int a = 0; a < 8; ++a) atomicAdd(&logits[(size_t)gr * 8 + a], pa[a]);
      }
    }
    __syncthreads();
  }
}

// ---- softmax over s (per (b,a) column) + orthogonality penalty via 8x8 Gram ----
__global__ __launch_bounds__(256) void softmax_pen(const float* __restrict__ logits,
                                                   const float* __restrict__ b_att,
                                                   float* __restrict__ attn,
                                                   float* __restrict__ pen) {
  __shared__ float sm[512 * 8];
  __shared__ float red[256];
  __shared__ float mx[8];
  __shared__ float dn[8];
  const int b = blockIdx.x, t = threadIdx.x;

  float ba[8];
#pragma unroll
  for (int a = 0; a < 8; ++a) ba[a] = b_att[a];

  // load logits[:, b, :] (+bias) into LDS, float4-vectorized
  const float4* lg = (const float4*)(logits + (size_t)b * 8);
  float4* sm4 = (float4*)sm;
#pragma unroll
  for (int i = 0; i < 4; ++i) {
    const int s = t * 2 + (i >> 1), piece = i & 1;
    float4 v = lg[(size_t)s * 128 + piece];
    v.x += ba[piece * 4 + 0]; v.y += ba[piece * 4 + 1];
    v.z += ba[piece * 4 + 2]; v.w += ba[piece * 4 + 3];
    sm4[s * 2 + piece] = v;
  }
  __syncthreads();

  const int a = t & 7, part = t >> 3; // 8 cols x 32 partials
  float m = -1e30f;
  for (int k = 0; k < 16; ++k) m = fmaxf(m, sm[(part + 32 * k) * 8 + a]);
  red[a * 32 + part] = m;
  __syncthreads();
  if (t < 8) {
    float mm = -1e30f;
    for (int p = 0; p < 32; ++p) mm = fmaxf(mm, red[t * 32 + p]);
    mx[t] = mm;
  }
  __syncthreads();

  float ps = 0.f;
  const float mxa = mx[a];
  for (int k = 0; k < 16; ++k) {
    const int idx = (part + 32 * k) * 8 + a;
    const float e = __expf(sm[idx] - mxa);
    sm[idx] = e;
    ps += e;
  }
  red[a * 32 + part] = ps;
  __syncthreads();
  if (t < 8) {
    float ss = 0.f;
    for (int p = 0; p < 32; ++p) ss += red[t * 32 + p];
    dn[t] = 1.f / ss;
  }
  __syncthreads();

  float dv[8];
#pragma unroll
  for (int i = 0; i < 8; ++i) dv[i] = dn[i];
  float4* ao = (float4*)(attn + (size_t)b * 8);
#pragma unroll
  for (int i = 0; i < 4; ++i) {
    const int s = t * 2 + (i >> 1), piece = i & 1;
    float4 v = sm4[s * 2 + piece];
    v.x *= dv[piece * 4 + 0]; v.y *= dv[piece * 4 + 1];
    v.z *= dv[piece * 4 + 2]; v.w *= dv[piece * 4 + 3];
    sm4[s * 2 + piece] = v;
    ao[(size_t)s * 128 + piece] = v;
  }
  __syncthreads();

  // penalty: M = A^T A (8x8); ||AA^T - I||_F^2 = ||M||_F^2 - 2 tr(M) + S
  if (t < 64) {
    const int ra = t >> 3, rb = t & 7;
    float Mv = 0.f;
    for (int s = 0; s < 512; ++s) Mv += sm[s * 8 + ra] * sm[s * 8 + rb];
    float c = Mv * Mv - (ra == rb ? 2.f * Mv : 0.f);
#pragma unroll
    for (int off = 32; off; off >>= 1) c += __shfl_down(c, off);
    if (t == 0) pen[b] = sqrtf(c + 512.f);
  }
}

// ---- attended[b, a, d] = sum_s attn[s,b,a] * x[s,b,d] ----
__global__ __launch_bounds__(256) void attended_k(const float* __restrict__ attn,
                                                  const float* __restrict__ x,
                                                  float* __restrict__ out) {
  __shared__ float at[512 * 8];
  const int b = blockIdx.x >> 2, dc = blockIdx.x & 3;
  const int t = threadIdx.x;

  const float4* ap = (const float4*)(attn + (size_t)b * 8);
  float4* at4 = (float4*)at;
#pragma unroll
  for (int i = 0; i < 4; ++i) {
    const int s = t * 2 + (i >> 1), piece = i & 1;
    at4[s * 2 + piece] = ap[(size_t)s * 128 + piece];
  }
  __syncthreads();

  const int d = dc * 256 + t;
  const float* xp = x + (size_t)b * kD + d;
  float acc[8] = {0.f, 0.f, 0.f, 0.f, 0.f, 0.f, 0.f, 0.f};
  for (int s0 = 0; s0 < 512; s0 += 4) {
    float xs[4];
#pragma unroll
    for (int ss = 0; ss < 4; ++ss) xs[ss] = xp[(size_t)(s0 + ss) * (kB * kD)];
#pragma unroll
    for (int ss = 0; ss < 4; ++ss) {
      const float4 p0 = at4[(s0 + ss) * 2];
      const float4 p1 = at4[(s0 + ss) * 2 + 1];
      acc[0] += p0.x * xs[ss]; acc[1] += p0.y * xs[ss];
      acc[2] += p0.z * xs[ss]; acc[3] += p0.w * xs[ss];
      acc[4] += p1.x * xs[ss]; acc[5] += p1.y * xs[ss];
      acc[6] += p1.z * xs[ss]; acc[7] += p1.w * xs[ss];
    }
  }
  float* op = out + (size_t)b * (kNH * kD) + d;
#pragma unroll
  for (int a = 0; a < 8; ++a) op[(size_t)a * kD] = acc[a];
}

__global__ void finalize_pen(const float* __restrict__ pen, float* __restrict__ out) {
  const int t = threadIdx.x;
  float v = pen[t];
#pragma unroll
  for (int off = 32; off; off >>= 1) v += __shfl_down(v, off);
  if (t == 0) out[(size_t)kB * kNH * kD] = v;
}

extern "C" void kernel_launch(void* const* d_in, const int* in_sizes, int n_in,
                              void* d_out, int out_size, void* d_ws, size_t ws_size,
                              hipStream_t stream) {
  const float* x     = (const float*)d_in[0]; // [S,B,D]
  const float* W_red = (const float*)d_in[1]; // [H,D]
  const float* b_red = (const float*)d_in[2]; // [H]
  const float* W_att = (const float*)d_in[3]; // [NH,H]
  const float* b_att = (const float*)d_in[4]; // [NH]
  float* out = (float*)d_out;

  char* ws = (char*)d_ws;
  unsigned short* Abf = (unsigned short*)ws;                         // 64 MB
  unsigned short* Wbf = (unsigned short*)(ws + (size_t)67108864);    // 4 MB
  float* logits = (float*)(ws + (size_t)71303168);                   // 1 MB
  float* attn   = (float*)(ws + (size_t)72351744);                   // 1 MB
  float* pen    = (float*)(ws + (size_t)73400320);                   // 256 B

  hipMemsetAsync(logits, 0, (size_t)kM * kNH * sizeof(float), stream);

  cvt_bf16<<<16384, 256, 0, stream>>>(x, Abf, (kM * kD) / 8);
  cvt_bf16<<<1024, 256, 0, stream>>>(W_red, Wbf, (kH * kD) / 8);

  gemm_fused<<<4096, 256, 0, stream>>>(Abf, Wbf, b_red, W_att, logits);

  softmax_pen<<<kB, 256, 0, stream>>>(logits, b_att, attn, pen);
  attended_k<<<kB * 4, 256, 0, stream>>>(attn, x, out);
  finalize_pen<<<1, 64, 0, stream>>>(pen, out);
}

// Round 3
// 1699.967 us; speedup vs baseline: 1.7076x; 1.7076x over previous
//
#include <hip/hip_runtime.h>
#include <hip/hip_bf16.h>
#include <math.h>

// Problem constants
constexpr int kS = 512, kB = 64, kD = 1024, kH = 2048, kNH = 8;
constexpr int kM = kS * kB; // 32768 GEMM rows (sb index)

typedef __attribute__((ext_vector_type(8))) short bf16x8;
typedef __attribute__((ext_vector_type(4))) float f32x4;

#define GLB(p) ((const __attribute__((address_space(1))) unsigned int*)(p))
#define LDSP(p) ((__attribute__((address_space(3))) unsigned int*)(p))

__device__ __forceinline__ unsigned short f2bf(float f) {
  unsigned int u = __builtin_bit_cast(unsigned int, f);
  unsigned int r = (u + 0x7fffu + ((u >> 16) & 1u)) >> 16;
  return (unsigned short)r;
}

// ---- fp32 -> bf16 conversion (memory-bound, 8 elems/thread) ----
__global__ __launch_bounds__(256) void cvt_bf16(const float* __restrict__ src,
                                                unsigned short* __restrict__ dst,
                                                int n8) {
  int i = blockIdx.x * 256 + threadIdx.x;
  if (i >= n8) return;
  const float4* s4 = (const float4*)src;
  float4 v0 = s4[2 * i], v1 = s4[2 * i + 1];
  union { unsigned short u[8]; float4 f2[2]; } o; // 16B store
  o.u[0] = f2bf(v0.x); o.u[1] = f2bf(v0.y); o.u[2] = f2bf(v0.z); o.u[3] = f2bf(v0.w);
  o.u[4] = f2bf(v1.x); o.u[5] = f2bf(v1.y); o.u[6] = f2bf(v1.z); o.u[7] = f2bf(v1.w);
  *(float4*)(dst + (size_t)i * 8) = o.f2[0];
}

// ---- GEMM1 (bf16 MFMA, BK=64, st_16x32-swizzled LDS) + relu/W_att epilogue ----
// st_16x32 (m201-verified): physical_byte = logical_byte ^ ((logical_byte>>9)&1)<<5.
// global_load_lds writes linearly, so the SOURCE address carries the inverse
// permutation (same involution); ds_read applies the XOR on its address.
// launch_bounds(256,3): VGPR cap ~170 incl AGPRs -> no accumulator spill
// (256,4 spilled acc to scratch: 13GB HBM traffic in round 2).
__global__ __launch_bounds__(256, 3) void gemm_fused(
    const unsigned short* __restrict__ Abf,   // [kM][kD] bf16
    const unsigned short* __restrict__ Wbf,   // [kH][kD] bf16
    const float* __restrict__ b_red,          // [kH]
    const float* __restrict__ W_att,          // [kNH][kH]
    float* __restrict__ logits)               // [kM][kNH] (pre-zeroed)
{
  __shared__ union {
    struct { unsigned short Ab[128 * 64]; unsigned short Bb[128 * 64]; } st; // 32 KB staging
    float et[32 * 132];                                                      // 16.9 KB epilogue tile
  } u;
  __shared__ float Wa[8 * 128]; // W_att slice for this n-tile

  const int tid = threadIdx.x;
  const int lane = tid & 63;
  const int w = tid >> 6;        // wave 0..3
  const int wr = w >> 1, wc = w & 1;

  // XCD-aware swizzle: each XCD owns 32 consecutive m-tiles x all 16 n-tiles
  int bid = blockIdx.x;
  int swz = (bid & 7) * 512 + (bid >> 3);
  const int nt = swz & 15, mt = swz >> 4;
  const int m0 = mt * 128, n0 = nt * 128;

  // staging addresses: wave w stages chunks ck = w*4+i (A) and same for B.
  // chunk = 8 rows x 64 shorts; lane covers (row = ck*8 + lane>>3, slot = lane&7).
  // dest byte P = ck*1024 + lane*16; bit9(P) = (ck*2 + (lane>>5)) & 1;
  // source 16B-slot = (lane&7) ^ (bit9<<1)  (inverse st_16x32).
  const unsigned short* gA[4];
  const unsigned short* gB[4];
#pragma unroll
  for (int i = 0; i < 4; ++i) {
    const int ck = w * 4 + i;
    const int row = ck * 8 + (lane >> 3);
    const int bit = (ck * 2 + (lane >> 5)) & 1;
    const int srcSeg = (lane & 7) ^ (bit << 1);
    gA[i] = Abf + (size_t)(m0 + row) * kD + srcSeg * 8;
    gB[i] = Wbf + (size_t)(n0 + row) * kD + srcSeg * 8;
  }

  f32x4 acc[4][4] = {};

  for (int kt = 0; kt < kD / 64; ++kt) {
#pragma unroll
    for (int i = 0; i < 4; ++i) {
      const int ck = w * 4 + i;
      __builtin_amdgcn_global_load_lds(GLB(gA[i]), LDSP(&u.st.Ab[ck * 512 + lane * 8]), 16, 0, 0);
      __builtin_amdgcn_global_load_lds(GLB(gB[i]), LDSP(&u.st.Bb[ck * 512 + lane * 8]), 16, 0, 0);
      gA[i] += 64; gB[i] += 64;
    }
    __syncthreads();

#pragma unroll
    for (int s = 0; s < 2; ++s) {
      bf16x8 aF[4], bF[4];
#pragma unroll
      for (int m = 0; m < 4; ++m) {
        const int row = wr * 64 + m * 16 + (lane & 15);
        int idx = row * 64 + (s * 4 + (lane >> 4)) * 8;
        idx ^= ((row >> 2) & 1) * 16; // st_16x32
        aF[m] = *(const bf16x8*)&u.st.Ab[idx];
      }
#pragma unroll
      for (int n = 0; n < 4; ++n) {
        const int row = wc * 64 + n * 16 + (lane & 15);
        int idx = row * 64 + (s * 4 + (lane >> 4)) * 8;
        idx ^= ((row >> 2) & 1) * 16;
        bF[n] = *(const bf16x8*)&u.st.Bb[idx];
      }
#pragma unroll
      for (int m = 0; m < 4; ++m)
#pragma unroll
        for (int n = 0; n < 4; ++n)
          acc[m][n] = __builtin_amdgcn_mfma_f32_16x16x32_bf16(aF[m], bF[n], acc[m][n], 0, 0, 0);
    }
    __syncthreads();
  }

  // ---- fused epilogue: logits[m0+r, a] += sum_h(relu(C+b_red)*W_att) ----
  // 4 chunks of 32 rows (keeps LDS union small -> 3 blocks/CU).
  float bias[4];
#pragma unroll
  for (int n = 0; n < 4; ++n) bias[n] = b_red[n0 + wc * 64 + n * 16 + (lane & 15)];

#pragma unroll 1
  for (int c = 0; c < 4; ++c) {
    if (wr == (c >> 1)) {
      // these 2 waves own rows c*32 .. c*32+31 of the C tile
#pragma unroll
      for (int m2 = 0; m2 < 2; ++m2) {
        const int m = (c & 1) * 2 + m2;
#pragma unroll
        for (int n = 0; n < 4; ++n) {
          const int colL = wc * 64 + n * 16 + (lane & 15);
#pragma unroll
          for (int j = 0; j < 4; ++j) {
            const int rowL = m2 * 16 + (lane >> 4) * 4 + j; // 0..31
            float v = acc[m][n][j] + bias[n];
            u.et[rowL * 132 + colL] = v > 0.f ? v : 0.f;
          }
        }
      }
    }
    if (c == 0 && wr == 1) {
      // waves 2,3 load the W_att slice meanwhile (only once)
      const int t = tid - 128; // 0..127
#pragma unroll
      for (int a = 0; a < 8; ++a) Wa[a * 128 + t] = W_att[a * kH + n0 + t];
    }
    __syncthreads();

    {
      const int row = tid >> 3;  // 0..31
      const int q = tid & 7;     // column eighth (strided)
      float pa[8] = {0.f, 0.f, 0.f, 0.f, 0.f, 0.f, 0.f, 0.f};
#pragma unroll
      for (int i = 0; i < 16; ++i) {
        const int col = q + i * 8;
        const float v = u.et[row * 132 + col];
#pragma unroll
        for (int a = 0; a < 8; ++a) pa[a] += v * Wa[a * 128 + col];
      }
#pragma unroll
      for (int a = 0; a < 8; ++a) {
        pa[a] += __shfl_xor(pa[a], 1);
        pa[a] += __shfl_xor(pa[a], 2);
        pa[a] += __shfl_xor(pa[a], 4);
      }
      if (q == 0) {
        const int gr = m0 + c * 32 + row;
#pragma unroll
        for (int a = 0; a < 8; ++a) atomicAdd(&logits[(size_t)gr * 8 + a], pa[a]);
      }
    }
    __syncthreads();
  }
}

// ---- softmax over s (per (b,a) column) + orthogonality penalty via 8x8 Gram ----
__global__ __launch_bounds__(256) void softmax_pen(const float* __restrict__ logits,
                                                   const float* __restrict__ b_att,
                                                   float* __restrict__ attn,
                                                   float* __restrict__ pen) {
  __shared__ float sm[512 * 8];
  __shared__ float red[256];
  __shared__ float mx[8];
  __shared__ float dn[8];
  const int b = blockIdx.x, t = threadIdx.x;

  float ba[8];
#pragma unroll
  for (int a = 0; a < 8; ++a) ba[a] = b_att[a];

  // load logits[:, b, :] (+bias) into LDS, float4-vectorized
  const float4* lg = (const float4*)(logits + (size_t)b * 8);
  float4* sm4 = (float4*)sm;
#pragma unroll
  for (int i = 0; i < 4; ++i) {
    const int s = t * 2 + (i >> 1), piece = i & 1;
    float4 v = lg[(size_t)s * 128 + piece];
    v.x += ba[piece * 4 + 0]; v.y += ba[piece * 4 + 1];
    v.z += ba[piece * 4 + 2]; v.w += ba[piece * 4 + 3];
    sm4[s * 2 + piece] = v;
  }
  __syncthreads();

  const int a = t & 7, part = t >> 3; // 8 cols x 32 partials
  float m = -1e30f;
  for (int k = 0; k < 16; ++k) m = fmaxf(m, sm[(part + 32 * k) * 8 + a]);
  red[a * 32 + part] = m;
  __syncthreads();
  if (t < 8) {
    float mm = -1e30f;
    for (int p = 0; p < 32; ++p) mm = fmaxf(mm, red[t * 32 + p]);
    mx[t] = mm;
  }
  __syncthreads();

  float ps = 0.f;
  const float mxa = mx[a];
  for (int k = 0; k < 16; ++k) {
    const int idx = (part + 32 * k) * 8 + a;
    const float e = __expf(sm[idx] - mxa);
    sm[idx] = e;
    ps += e;
  }
  red[a * 32 + part] = ps;
  __syncthreads();
  if (t < 8) {
    float ss = 0.f;
    for (int p = 0; p < 32; ++p) ss += red[t * 32 + p];
    dn[t] = 1.f / ss;
  }
  __syncthreads();

  float dv[8];
#pragma unroll
  for (int i = 0; i < 8; ++i) dv[i] = dn[i];
  float4* ao = (float4*)(attn + (size_t)b * 8);
#pragma unroll
  for (int i = 0; i < 4; ++i) {
    const int s = t * 2 + (i >> 1), piece = i & 1;
    float4 v = sm4[s * 2 + piece];
    v.x *= dv[piece * 4 + 0]; v.y *= dv[piece * 4 + 1];
    v.z *= dv[piece * 4 + 2]; v.w *= dv[piece * 4 + 3];
    sm4[s * 2 + piece] = v;
    ao[(size_t)s * 128 + piece] = v;
  }
  __syncthreads();

  // penalty: M = A^T A (8x8); ||AA^T - I||_F^2 = ||M||_F^2 - 2 tr(M) + S
  if (t < 64) {
    const int ra = t >> 3, rb = t & 7;
    float Mv = 0.f;
    for (int s = 0; s < 512; ++s) Mv += sm[s * 8 + ra] * sm[s * 8 + rb];
    float c = Mv * Mv - (ra == rb ? 2.f * Mv : 0.f);
#pragma unroll
    for (int off = 32; off; off >>= 1) c += __shfl_down(c, off);
    if (t == 0) pen[b] = sqrtf(c + 512.f);
  }
}

// ---- attended[b, a, d] = sum_s attn[s,b,a] * x[s,b,d] ----
__global__ __launch_bounds__(256) void attended_k(const float* __restrict__ attn,
                                                  const float* __restrict__ x,
                                                  float* __restrict__ out) {
  __shared__ float at[512 * 8];
  const int b = blockIdx.x >> 2, dc = blockIdx.x & 3;
  const int t = threadIdx.x;

  const float4* ap = (const float4*)(attn + (size_t)b * 8);
  float4* at4 = (float4*)at;
#pragma unroll
  for (int i = 0; i < 4; ++i) {
    const int s = t * 2 + (i >> 1), piece = i & 1;
    at4[s * 2 + piece] = ap[(size_t)s * 128 + piece];
  }
  __syncthreads();

  const int d = dc * 256 + t;
  const float* xp = x + (size_t)b * kD + d;
  float acc[8] = {0.f, 0.f, 0.f, 0.f, 0.f, 0.f, 0.f, 0.f};
  for (int s0 = 0; s0 < 512; s0 += 4) {
    float xs[4];
#pragma unroll
    for (int ss = 0; ss < 4; ++ss) xs[ss] = xp[(size_t)(s0 + ss) * (kB * kD)];
#pragma unroll
    for (int ss = 0; ss < 4; ++ss) {
      const float4 p0 = at4[(s0 + ss) * 2];
      const float4 p1 = at4[(s0 + ss) * 2 + 1];
      acc[0] += p0.x * xs[ss]; acc[1] += p0.y * xs[ss];
      acc[2] += p0.z * xs[ss]; acc[3] += p0.w * xs[ss];
      acc[4] += p1.x * xs[ss]; acc[5] += p1.y * xs[ss];
      acc[6] += p1.z * xs[ss]; acc[7] += p1.w * xs[ss];
    }
  }
  float* op = out + (size_t)b * (kNH * kD) + d;
#pragma unroll
  for (int a = 0; a < 8; ++a) op[(size_t)a * kD] = acc[a];
}

__global__ void finalize_pen(const float* __restrict__ pen, float* __restrict__ out) {
  const int t = threadIdx.x;
  float v = pen[t];
#pragma unroll
  for (int off = 32; off; off >>= 1) v += __shfl_down(v, off);
  if (t == 0) out[(size_t)kB * kNH * kD] = v;
}

extern "C" void kernel_launch(void* const* d_in, const int* in_sizes, int n_in,
                              void* d_out, int out_size, void* d_ws, size_t ws_size,
                              hipStream_t stream) {
  const float* x     = (const float*)d_in[0]; // [S,B,D]
  const float* W_red = (const float*)d_in[1]; // [H,D]
  const float* b_red = (const float*)d_in[2]; // [H]
  const float* W_att = (const float*)d_in[3]; // [NH,H]
  const float* b_att = (const float*)d_in[4]; // [NH]
  float* out = (float*)d_out;

  char* ws = (char*)d_ws;
  unsigned short* Abf = (unsigned short*)ws;                         // 64 MB
  unsigned short* Wbf = (unsigned short*)(ws + (size_t)67108864);    // 4 MB
  float* logits = (float*)(ws + (size_t)71303168);                   // 1 MB
  float* attn   = (float*)(ws + (size_t)72351744);                   // 1 MB
  float* pen    = (float*)(ws + (size_t)73400320);                   // 256 B

  hipMemsetAsync(logits, 0, (size_t)kM * kNH * sizeof(float), stream);

  cvt_bf16<<<16384, 256, 0, stream>>>(x, Abf, (kM * kD) / 8);
  cvt_bf16<<<1024, 256, 0, stream>>>(W_red, Wbf, (kH * kD) / 8);

  gemm_fused<<<4096, 256, 0, stream>>>(Abf, Wbf, b_red, W_att, logits);

  softmax_pen<<<kB, 256, 0, stream>>>(logits, b_att, attn, pen);
  attended_k<<<kB * 4, 256, 0, stream>>>(attn, x, out);
  finalize_pen<<<1, 64, 0, stream>>>(pen, out);
}

// Round 4
// 624.368 us; speedup vs baseline: 4.6494x; 2.7227x over previous
//
#include <hip/hip_runtime.h>
#include <hip/hip_bf16.h>
#include <math.h>

// Problem constants
constexpr int kS = 512, kB = 64, kD = 1024, kH = 2048, kNH = 8;
constexpr int kM = kS * kB; // 32768 GEMM rows (sb index)

typedef __attribute__((ext_vector_type(8))) short bf16x8;
typedef __attribute__((ext_vector_type(4))) float f32x4;

#define GLB(p) ((const __attribute__((address_space(1))) unsigned int*)(p))
#define LDSP(p) ((__attribute__((address_space(3))) unsigned int*)(p))

__device__ __forceinline__ unsigned short f2bf(float f) {
  unsigned int u = __builtin_bit_cast(unsigned int, f);
  unsigned int r = (u + 0x7fffu + ((u >> 16) & 1u)) >> 16;
  return (unsigned short)r;
}

// ---- fp32 -> bf16 conversion (memory-bound, 8 elems/thread) ----
__global__ __launch_bounds__(256) void cvt_bf16(const float* __restrict__ src,
                                                unsigned short* __restrict__ dst,
                                                int n8) {
  int i = blockIdx.x * 256 + threadIdx.x;
  if (i >= n8) return;
  const float4* s4 = (const float4*)src;
  float4 v0 = s4[2 * i], v1 = s4[2 * i + 1];
  union { unsigned short u[8]; float4 f2[2]; } o; // 16B store
  o.u[0] = f2bf(v0.x); o.u[1] = f2bf(v0.y); o.u[2] = f2bf(v0.z); o.u[3] = f2bf(v0.w);
  o.u[4] = f2bf(v1.x); o.u[5] = f2bf(v1.y); o.u[6] = f2bf(v1.z); o.u[7] = f2bf(v1.w);
  *(float4*)(dst + (size_t)i * 8) = o.f2[0];
}

// ---- GEMM1 (bf16 MFMA, BK=64) + relu/W_att fused epilogue ----
// LDS swizzle (G4/m214 pattern): within each 128B row, physical 16B slot =
// logical slot ^ (row & 7). Both-sides: global_load_lds dest is LINEAR;
// the lane's GLOBAL source slot carries the inverse ((lane&7)^(lane>>3),
// since dest row&7 == lane>>3); ds_read XORs its slot with (row&7)==(lane&7).
// 16 consecutive rows then cover all 8 slots exactly twice -> 2-way = free.
// EPILOGUE IS FULLY UNROLLED: runtime-indexing acc[] (round 3's `m=(c&1)*2+m2`
// with non-unrolled c) demotes the accumulator to scratch (rule #20): 4.6 GB
// of scratch traffic. Every acc index must be compile-time.
__global__ __launch_bounds__(256, 3) void gemm_fused(
    const unsigned short* __restrict__ Abf,   // [kM][kD] bf16
    const unsigned short* __restrict__ Wbf,   // [kH][kD] bf16
    const float* __restrict__ b_red,          // [kH]
    const float* __restrict__ W_att,          // [kNH][kH]
    float* __restrict__ logits)               // [kM][kNH] (pre-zeroed)
{
  __shared__ union {
    struct { unsigned short Ab[128 * 64]; unsigned short Bb[128 * 64]; } st; // 32 KB staging
    float et[32 * 132];                                                      // 16.9 KB epilogue tile
  } u;
  __shared__ float Wa[8 * 128]; // W_att slice for this n-tile

  const int tid = threadIdx.x;
  const int lane = tid & 63;
  const int w = tid >> 6;        // wave 0..3
  const int wr = w >> 1, wc = w & 1;

  // XCD-aware swizzle: each XCD owns 32 consecutive m-tiles x all 16 n-tiles
  int bid = blockIdx.x;
  int swz = (bid & 7) * 512 + (bid >> 3);
  const int nt = swz & 15, mt = swz >> 4;
  const int m0 = mt * 128, n0 = nt * 128;

  // staging: wave w stages chunks ck = w*4+i; chunk = 8 rows x 128B.
  // dest (linear) = ck*1024B + lane*16B -> row = ck*8 + (lane>>3), slot = lane&7.
  // source slot = (lane&7) ^ (row&7) = (lane&7) ^ (lane>>3).
  const unsigned short* gA[4];
  const unsigned short* gB[4];
#pragma unroll
  for (int i = 0; i < 4; ++i) {
    const int ck = w * 4 + i;
    const int row = ck * 8 + (lane >> 3);
    const int srcSlot = (lane & 7) ^ (lane >> 3);
    gA[i] = Abf + (size_t)(m0 + row) * kD + srcSlot * 8;
    gB[i] = Wbf + (size_t)(n0 + row) * kD + srcSlot * 8;
  }

  f32x4 acc[4][4] = {};

  for (int kt = 0; kt < kD / 64; ++kt) {
#pragma unroll
    for (int i = 0; i < 4; ++i) {
      const int ck = w * 4 + i;
      __builtin_amdgcn_global_load_lds(GLB(gA[i]), LDSP(&u.st.Ab[ck * 512 + lane * 8]), 16, 0, 0);
      __builtin_amdgcn_global_load_lds(GLB(gB[i]), LDSP(&u.st.Bb[ck * 512 + lane * 8]), 16, 0, 0);
      gA[i] += 64; gB[i] += 64;
    }
    __syncthreads();

#pragma unroll
    for (int s = 0; s < 2; ++s) {
      // fragment rows == (lane&15) mod 8 == lane&7 for every m/n (offsets are
      // multiples of 8), so the slot XOR hoists out of the m/n loops.
      const int slot = (s * 4 + (lane >> 4)) ^ (lane & 7);
      bf16x8 aF[4], bF[4];
#pragma unroll
      for (int m = 0; m < 4; ++m) {
        const int row = wr * 64 + m * 16 + (lane & 15);
        aF[m] = *(const bf16x8*)&u.st.Ab[row * 64 + slot * 8];
      }
#pragma unroll
      for (int n = 0; n < 4; ++n) {
        const int row = wc * 64 + n * 16 + (lane & 15);
        bF[n] = *(const bf16x8*)&u.st.Bb[row * 64 + slot * 8];
      }
#pragma unroll
      for (int m = 0; m < 4; ++m)
#pragma unroll
        for (int n = 0; n < 4; ++n)
          acc[m][n] = __builtin_amdgcn_mfma_f32_16x16x32_bf16(aF[m], bF[n], acc[m][n], 0, 0, 0);
    }
    __syncthreads();
  }

  // ---- fused epilogue: logits[m0+r, a] += sum_h(relu(C+b_red)*W_att) ----
  // 4 chunks of 32 rows; FULLY unrolled so all acc indices are static.
  float bias[4];
#pragma unroll
  for (int n = 0; n < 4; ++n) bias[n] = b_red[n0 + wc * 64 + n * 16 + (lane & 15)];

#pragma unroll
  for (int c = 0; c < 4; ++c) {
    if (wr == (c >> 1)) {
      // these 2 waves own rows c*32 .. c*32+31 of the C tile
#pragma unroll
      for (int m2 = 0; m2 < 2; ++m2) {
        const int m = (c & 1) * 2 + m2;
#pragma unroll
        for (int n = 0; n < 4; ++n) {
          const int colL = wc * 64 + n * 16 + (lane & 15);
#pragma unroll
          for (int j = 0; j < 4; ++j) {
            const int rowL = m2 * 16 + (lane >> 4) * 4 + j; // 0..31
            float v = acc[m][n][j] + bias[n];
            u.et[rowL * 132 + colL] = v > 0.f ? v : 0.f;
          }
        }
      }
    }
    if (c == 0 && wr == 1) {
      // waves 2,3 load the W_att slice meanwhile (only once)
      const int t = tid - 128; // 0..127
#pragma unroll
      for (int a = 0; a < 8; ++a) Wa[a * 128 + t] = W_att[a * kH + n0 + t];
    }
    __syncthreads();

    {
      const int row = tid >> 3;  // 0..31
      const int q = tid & 7;     // column eighth (strided)
      float pa[8] = {0.f, 0.f, 0.f, 0.f, 0.f, 0.f, 0.f, 0.f};
#pragma unroll
      for (int i = 0; i < 16; ++i) {
        const int col = q + i * 8;
        const float v = u.et[row * 132 + col];
#pragma unroll
        for (int a = 0; a < 8; ++a) pa[a] += v * Wa[a * 128 + col];
      }
#pragma unroll
      for (int a = 0; a < 8; ++a) {
        pa[a] += __shfl_xor(pa[a], 1);
        pa[a] += __shfl_xor(pa[a], 2);
        pa[a] += __shfl_xor(pa[a], 4);
      }
      if (q == 0) {
        const int gr = m0 + c * 32 + row;
#pragma unroll
        for (int a = 0; a < 8; ++a) atomicAdd(&logits[(size_t)gr * 8 + a], pa[a]);
      }
    }
    __syncthreads();
  }
}

// ---- softmax over s (per (b,a) column) + orthogonality penalty via 8x8 Gram ----
__global__ __launch_bounds__(256) void softmax_pen(const float* __restrict__ logits,
                                                   const float* __restrict__ b_att,
                                                   float* __restrict__ attn,
                                                   float* __restrict__ pen) {
  __shared__ float sm[512 * 8];
  __shared__ float red[256];
  __shared__ float mx[8];
  __shared__ float dn[8];
  const int b = blockIdx.x, t = threadIdx.x;

  float ba[8];
#pragma unroll
  for (int a = 0; a < 8; ++a) ba[a] = b_att[a];

  // load logits[:, b, :] (+bias) into LDS, float4-vectorized
  const float4* lg = (const float4*)(logits + (size_t)b * 8);
  float4* sm4 = (float4*)sm;
#pragma unroll
  for (int i = 0; i < 4; ++i) {
    const int s = t * 2 + (i >> 1), piece = i & 1;
    float4 v = lg[(size_t)s * 128 + piece];
    v.x += ba[piece * 4 + 0]; v.y += ba[piece * 4 + 1];
    v.z += ba[piece * 4 + 2]; v.w += ba[piece * 4 + 3];
    sm4[s * 2 + piece] = v;
  }
  __syncthreads();

  const int a = t & 7, part = t >> 3; // 8 cols x 32 partials
  float m = -1e30f;
  for (int k = 0; k < 16; ++k) m = fmaxf(m, sm[(part + 32 * k) * 8 + a]);
  red[a * 32 + part] = m;
  __syncthreads();
  if (t < 8) {
    float mm = -1e30f;
    for (int p = 0; p < 32; ++p) mm = fmaxf(mm, red[t * 32 + p]);
    mx[t] = mm;
  }
  __syncthreads();

  float ps = 0.f;
  const float mxa = mx[a];
  for (int k = 0; k < 16; ++k) {
    const int idx = (part + 32 * k) * 8 + a;
    const float e = __expf(sm[idx] - mxa);
    sm[idx] = e;
    ps += e;
  }
  red[a * 32 + part] = ps;
  __syncthreads();
  if (t < 8) {
    float ss = 0.f;
    for (int p = 0; p < 32; ++p) ss += red[t * 32 + p];
    dn[t] = 1.f / ss;
  }
  __syncthreads();

  float dv[8];
#pragma unroll
  for (int i = 0; i < 8; ++i) dv[i] = dn[i];
  float4* ao = (float4*)(attn + (size_t)b * 8);
#pragma unroll
  for (int i = 0; i < 4; ++i) {
    const int s = t * 2 + (i >> 1), piece = i & 1;
    float4 v = sm4[s * 2 + piece];
    v.x *= dv[piece * 4 + 0]; v.y *= dv[piece * 4 + 1];
    v.z *= dv[piece * 4 + 2]; v.w *= dv[piece * 4 + 3];
    sm4[s * 2 + piece] = v;
    ao[(size_t)s * 128 + piece] = v;
  }
  __syncthreads();

  // penalty: M = A^T A (8x8); ||AA^T - I||_F^2 = ||M||_F^2 - 2 tr(M) + S
  if (t < 64) {
    const int ra = t >> 3, rb = t & 7;
    float Mv = 0.f;
    for (int s = 0; s < 512; ++s) Mv += sm[s * 8 + ra] * sm[s * 8 + rb];
    float c = Mv * Mv - (ra == rb ? 2.f * Mv : 0.f);
#pragma unroll
    for (int off = 32; off; off >>= 1) c += __shfl_down(c, off);
    if (t == 0) pen[b] = sqrtf(c + 512.f);
  }
}

// ---- attended[b, a, d] = sum_s attn[s,b,a] * x[s,b,d] ----
__global__ __launch_bounds__(256) void attended_k(const float* __restrict__ attn,
                                                  const float* __restrict__ x,
                                                  float* __restrict__ out) {
  __shared__ float at[512 * 8];
  const int b = blockIdx.x >> 2, dc = blockIdx.x & 3;
  const int t = threadIdx.x;

  const float4* ap = (const float4*)(attn + (size_t)b * 8);
  float4* at4 = (float4*)at;
#pragma unroll
  for (int i = 0; i < 4; ++i) {
    const int s = t * 2 + (i >> 1), piece = i & 1;
    at4[s * 2 + piece] = ap[(size_t)s * 128 + piece];
  }
  __syncthreads();

  const int d = dc * 256 + t;
  const float* xp = x + (size_t)b * kD + d;
  float acc[8] = {0.f, 0.f, 0.f, 0.f, 0.f, 0.f, 0.f, 0.f};
  for (int s0 = 0; s0 < 512; s0 += 4) {
    float xs[4];
#pragma unroll
    for (int ss = 0; ss < 4; ++ss) xs[ss] = xp[(size_t)(s0 + ss) * (kB * kD)];
#pragma unroll
    for (int ss = 0; ss < 4; ++ss) {
      const float4 p0 = at4[(s0 + ss) * 2];
      const float4 p1 = at4[(s0 + ss) * 2 + 1];
      acc[0] += p0.x * xs[ss]; acc[1] += p0.y * xs[ss];
      acc[2] += p0.z * xs[ss]; acc[3] += p0.w * xs[ss];
      acc[4] += p1.x * xs[ss]; acc[5] += p1.y * xs[ss];
      acc[6] += p1.z * xs[ss]; acc[7] += p1.w * xs[ss];
    }
  }
  float* op = out + (size_t)b * (kNH * kD) + d;
#pragma unroll
  for (int a = 0; a < 8; ++a) op[(size_t)a * kD] = acc[a];
}

__global__ void finalize_pen(const float* __restrict__ pen, float* __restrict__ out) {
  const int t = threadIdx.x;
  float v = pen[t];
#pragma unroll
  for (int off = 32; off; off >>= 1) v += __shfl_down(v, off);
  if (t == 0) out[(size_t)kB * kNH * kD] = v;
}

extern "C" void kernel_launch(void* const* d_in, const int* in_sizes, int n_in,
                              void* d_out, int out_size, void* d_ws, size_t ws_size,
                              hipStream_t stream) {
  const float* x     = (const float*)d_in[0]; // [S,B,D]
  const float* W_red = (const float*)d_in[1]; // [H,D]
  const float* b_red = (const float*)d_in[2]; // [H]
  const float* W_att = (const float*)d_in[3]; // [NH,H]
  const float* b_att = (const float*)d_in[4]; // [NH]
  float* out = (float*)d_out;

  char* ws = (char*)d_ws;
  unsigned short* Abf = (unsigned short*)ws;                         // 64 MB
  unsigned short* Wbf = (unsigned short*)(ws + (size_t)67108864);    // 4 MB
  float* logits = (float*)(ws + (size_t)71303168);                   // 1 MB
  float* attn   = (float*)(ws + (size_t)72351744);                   // 1 MB
  float* pen    = (float*)(ws + (size_t)73400320);                   // 256 B

  hipMemsetAsync(logits, 0, (size_t)kM * kNH * sizeof(float), stream);

  cvt_bf16<<<16384, 256, 0, stream>>>(x, Abf, (kM * kD) / 8);
  cvt_bf16<<<1024, 256, 0, stream>>>(W_red, Wbf, (kH * kD) / 8);

  gemm_fused<<<4096, 256, 0, stream>>>(Abf, Wbf, b_red, W_att, logits);

  softmax_pen<<<kB, 256, 0, stream>>>(logits, b_att, attn, pen);
  attended_k<<<kB * 4, 256, 0, stream>>>(attn, x, out);
  finalize_pen<<<1, 64, 0, stream>>>(pen, out);
}